// Round 17
// baseline (155.207 us; speedup 1.0000x reference)
//
#include <hip/hip_runtime.h>

#define Tt 2048
#define Cc 512
#define Bb 4
#define BC (Bb * Cc)

typedef __attribute__((ext_vector_type(4))) float f32x4;
typedef __attribute__((ext_vector_type(8))) _Float16 f16x8;
typedef __attribute__((ext_vector_type(4))) _Float16 f16x4;
typedef __attribute__((ext_vector_type(2))) _Float16 f16x2;

// async global->LDS 16B copy: dest = wave-uniform LDS base + lane*16.
__device__ static inline void gl16(const _Float16* g, _Float16* l)
{
    __builtin_amdgcn_global_load_lds(
        (const __attribute__((address_space(1))) void*)g,
        (__attribute__((address_space(3))) void*)l, 16, 0, 0);
}

// ---------------------------------------------------------------------------
// Kernel P: fused prep — blocks [0,2048): HS fp32->fp16; [2048,2304):
// W transpose->Wt fp16; [2304,2307): colsum zero.
// ---------------------------------------------------------------------------
__global__ __launch_bounds__(256) void prep(
    const float* __restrict__ Wq, const float* __restrict__ Wk,
    const float* __restrict__ Wv, const float* __restrict__ Wo,
    const float* __restrict__ HS, _Float16* __restrict__ Wt,
    _Float16* __restrict__ HSh, float* __restrict__ colsum)
{
    const int blk = blockIdx.x;
    const int tid = threadIdx.x;
    __shared__ float tile[64][65];

    if (blk < 2048) {
        const size_t i = ((size_t)blk * 256 + tid) * 8;
        float4 a = *(const float4*)&HS[i];
        float4 b = *(const float4*)&HS[i + 4];
        f16x8 o;
        o[0] = (_Float16)a.x; o[1] = (_Float16)a.y;
        o[2] = (_Float16)a.z; o[3] = (_Float16)a.w;
        o[4] = (_Float16)b.x; o[5] = (_Float16)b.y;
        o[6] = (_Float16)b.z; o[7] = (_Float16)b.w;
        *(f16x8*)&HSh[i] = o;
    } else if (blk < 2304) {
        const int lb = blk - 2048;
        const int z = lb >> 6, x = lb & 63;
        const float* W = (z == 0) ? Wq : (z == 1) ? Wk : (z == 2) ? Wv : Wo;
        const int k0 = (x >> 3) * 64, n0 = (x & 7) * 64;
#pragma unroll
        for (int i = 0; i < 4; ++i) {
            const int idx = i * 256 + tid;
            const int kr = idx >> 4, c4 = idx & 15;
            float4 v = *(const float4*)&W[(size_t)(k0 + kr) * Cc + n0 + c4 * 4];
            tile[kr][c4 * 4 + 0] = v.x; tile[kr][c4 * 4 + 1] = v.y;
            tile[kr][c4 * 4 + 2] = v.z; tile[kr][c4 * 4 + 3] = v.w;
        }
        __syncthreads();
#pragma unroll
        for (int i = 0; i < 4; ++i) {
            const int idx = i * 256 + tid;
            const int nr = idx >> 4, k4 = idx & 15;
            f16x4 o;
            o[0] = (_Float16)tile[k4 * 4 + 0][nr];
            o[1] = (_Float16)tile[k4 * 4 + 1][nr];
            o[2] = (_Float16)tile[k4 * 4 + 2][nr];
            o[3] = (_Float16)tile[k4 * 4 + 3][nr];
            *(f16x4*)&Wt[((size_t)(z * 512 + n0 + nr)) * Cc + k0 + k4 * 4] = o;
        }
    } else {
        const int i = (blk - 2304) * 2048 + tid * 8;
        *(f32x4*)&colsum[i]     = (f32x4){0.f, 0.f, 0.f, 0.f};
        *(f32x4*)&colsum[i + 4] = (f32x4){0.f, 0.f, 0.f, 0.f};
    }
}

// ---------------------------------------------------------------------------
// Kernel 1: QKV GEMM, fp16 MFMA, 128x128 tile, 4 waves, BK=64 (two 32-wide
// sub-steps staged into four separate [128][32] linear slabs): 8 gl16s in
// flight per vmcnt(0)+barrier drain instead of 4, barrier pairs halved
// 16 -> 8 (amortizes the m97 barrier-drain stall; LDS footprint and read
// pattern unchanged). Epilogue: Q/K fp16 store; V (z==2) written DIRECTLY
// as VT (transposed + kappa key-permutation) via an LDS bounce. All z
// accumulate per-(b,channel) sum-of-squares.
// ---------------------------------------------------------------------------
__global__ __launch_bounds__(256, 3) void qkv_mfma(
    const _Float16* __restrict__ HSh, const _Float16* __restrict__ Wt,
    _Float16* __restrict__ Qf, _Float16* __restrict__ Kf,
    _Float16* __restrict__ VTh, float* __restrict__ colsum)
{
    const int mt = blockIdx.x;              // 64
    const int nt = blockIdx.y;              // 4
    const int z  = blockIdx.z;              // 3

    const int tid = threadIdx.x;
    const int wave = tid >> 6, lane = tid & 63;
    const int quad = lane >> 4, lm = lane & 15;
    const int wm = (wave & 1) * 64, wn = (wave >> 1) * 64;

    // unified LDS: staging uses 4 slabs x 4096 halves = 32 KB; epilogue
    // transpose uses the full 128*136 halves (34.8 KB).
    __shared__ _Float16 smem[128 * 136];
    _Float16* sAa = smem;                   // k-half 0, A
    _Float16* sAb = smem + 4096;            // k-half 1, A
    _Float16* sBa = smem + 8192;            // k-half 0, B
    _Float16* sBb = smem + 12288;           // k-half 1, B

    f32x4 acc[4][4];
#pragma unroll
    for (int mf = 0; mf < 4; ++mf)
#pragma unroll
        for (int nf = 0; nf < 4; ++nf) acc[mf][nf] = (f32x4){0.f, 0.f, 0.f, 0.f};

    const int lr = lane >> 2;
    const int lc = (lane & 3) * 8;
    const _Float16* gaA = HSh + (size_t)(mt * 128 + wave * 32 + lr) * Cc + lc;
    const _Float16* gaB = Wt + ((size_t)(z * 512 + nt * 128 + wave * 32 + lr)) * Cc + lc;
    const int wofs = wave * 1024;

    for (int k0 = 0; k0 < Cc; k0 += 64) {
        __syncthreads();
        gl16(gaA + k0,                 sAa + wofs);
        gl16(gaA + 16 * Cc + k0,       sAa + wofs + 512);
        gl16(gaA + k0 + 32,            sAb + wofs);
        gl16(gaA + 16 * Cc + k0 + 32,  sAb + wofs + 512);
        gl16(gaB + k0,                 sBa + wofs);
        gl16(gaB + 16 * Cc + k0,       sBa + wofs + 512);
        gl16(gaB + k0 + 32,            sBb + wofs);
        gl16(gaB + 16 * Cc + k0 + 32,  sBb + wofs + 512);
        __syncthreads();

#pragma unroll
        for (int kk = 0; kk < 2; ++kk) {
            const _Float16* sA = kk ? sAb : sAa;
            const _Float16* sB = kk ? sBb : sBa;
            f16x8 ah[4], bh[4];
#pragma unroll
            for (int mf = 0; mf < 4; ++mf)
                ah[mf] = *(const f16x8*)&sA[(wm + mf * 16 + lm) * 32 + quad * 8];
#pragma unroll
            for (int nf = 0; nf < 4; ++nf)
                bh[nf] = *(const f16x8*)&sB[(wn + nf * 16 + lm) * 32 + quad * 8];
#pragma unroll
            for (int mf = 0; mf < 4; ++mf)
#pragma unroll
                for (int nf = 0; nf < 4; ++nf)
                    acc[mf][nf] = __builtin_amdgcn_mfma_f32_16x16x32_f16(ah[mf], bh[nf], acc[mf][nf], 0, 0, 0);
        }
    }

    const int bidx = mt >> 4;

    // ---- colsum (all z) + Q/K store (z < 2)
    _Float16* Out = (z == 0) ? Qf : Kf;
#pragma unroll
    for (int nf = 0; nf < 4; ++nf) {
        float cs = 0.f;
#pragma unroll
        for (int mf = 0; mf < 4; ++mf)
#pragma unroll
            for (int r = 0; r < 4; ++r) {
                const float v = acc[mf][nf][r];
                cs += v * v;
                if (z < 2) {
                    const size_t idx =
                        (size_t)(mt * 128 + wm + mf * 16 + quad * 4 + r) * Cc +
                        nt * 128 + wn + nf * 16 + lm;
                    Out[idx] = (_Float16)v;
                }
            }
        cs += __shfl_xor(cs, 16, 64);
        cs += __shfl_xor(cs, 32, 64);
        if (lane < 16)
            atomicAdd(&colsum[(size_t)z * BC + bidx * Cc + nt * 128 + wn + nf * 16 + lane], cs);
    }

    // ---- z == 2: write V transposed (VT[b][c][t'], kappa-permuted t) via LDS
    if (z == 2) {
        __syncthreads();            // staging done; reuse smem as TL[c][t']
#pragma unroll
        for (int nf = 0; nf < 4; ++nf) {
            const int c = wn + nf * 16 + lm;
#pragma unroll
            for (int mf = 0; mf < 4; ++mf) {
                const int m0 = wm + mf * 16 + quad * 4;     // +r, r=0..3
                const int tl = m0 & 63;
                const int u = tl >> 3, j0 = tl & 7;
                const int p0 = ((u >> 2) & 1) * 32 + (u & 1) * 16 +
                               ((u >> 1) & 1) * 4 + ((j0 >= 4) ? 8 : 0);
                const int tperm = (m0 & 64) + p0;
                f16x4 pk;
#pragma unroll
                for (int r = 0; r < 4; ++r) pk[r] = (_Float16)acc[mf][nf][r];
                *(f16x4*)&smem[c * 136 + tperm] = pk;
            }
        }
        __syncthreads();
        // phase B: coalesced f16x8 stores to VT
        const int b = mt >> 4;
        const int tbase = (mt & 15) * 128;
#pragma unroll
        for (int i = 0; i < 8; ++i) {
            const int idx = i * 256 + tid;
            const int cr = idx >> 4, t8 = (idx & 15) * 8;
            f16x8 v = *(const f16x8*)&smem[cr * 136 + t8];
            *(f16x8*)&VTh[((size_t)(b * Cc) + nt * 128 + cr) * Tt + tbase + t8] = v;
        }
    }
}

// ---------------------------------------------------------------------------
// Kernel 4: fp16 MFMA flash attention (best measured: 47.2 us). 4 waves,
// 32 q/wave, BK=64 double-buffered reg staging, cross-iteration pipeline
// (QK(kt) | PV(kt-1) | exp(kt)), P in regs via pre-permuted VT, l via
// ones-MFMA, setprio on MFMA clusters, XCD-local 1-D grid.
// inv_norm fused: iq/ik/iv computed inline from colsum (rsqrt).
// ---------------------------------------------------------------------------
#define LSTR 72

__global__ __launch_bounds__(256, 3) void attn_mfma(
    const _Float16* __restrict__ Qf, const _Float16* __restrict__ Kf,
    const _Float16* __restrict__ VT, const float* __restrict__ colsum,
    _Float16* __restrict__ AO)
{
    const int bid = blockIdx.x;           // 512
    const int qt = bid >> 5;              // 16
    const int bh = bid & 31;              // 32 (bid%8 == bh%8 -> XCD locality)
    const int b = bh >> 3, h = bh & 7;
    const int tid = threadIdx.x;
    const int wave = tid >> 6, lane = tid & 63;
    const int quad = lane >> 4, lm = lane & 15;
    const float invT = 1.0f / Tt;

    __shared__ _Float16 sK[2][64 * LSTR];
    __shared__ _Float16 sVT[2][64 * LSTR];

    // ---- per-channel scale iq*ik*0.125*log2(e), computed from colsum inline
    float ss[2][8];
    {
        const float* csq = colsum + b * Cc + h * 64;
        const float* csk = colsum + BC + b * Cc + h * 64;
#pragma unroll
        for (int ks = 0; ks < 2; ++ks) {
            const int d0 = ks * 32 + quad * 8;
#pragma unroll
            for (int j = 0; j < 8; ++j) {
                const float iq = rsqrtf(csq[d0 + j] * invT + 1e-4f);
                const float ik = rsqrtf(csk[d0 + j] * invT + 1e-4f);
                ss[ks][j] = iq * ik * 0.18033688011f;
            }
        }
    }

    // ---- Q fragments (B-operand: n=lm=query, k=quad*8+j)
    f16x8 qb[2][2];
    {
#pragma unroll
        for (int qf = 0; qf < 2; ++qf) {
            const int row = qt * 128 + wave * 32 + qf * 16 + lm;
#pragma unroll
            for (int ks = 0; ks < 2; ++ks) {
                const int d0 = ks * 32 + quad * 8;
                f16x8 qv = *(const f16x8*)&Qf[(size_t)(b * Tt + row) * Cc + h * 64 + d0];
#pragma unroll
                for (int j = 0; j < 8; ++j)
                    qb[qf][ks][j] = (_Float16)((float)qv[j] * ss[ks][j]);
            }
        }
    }

    f32x4 o[4][2];
#pragma unroll
    for (int cf = 0; cf < 4; ++cf)
#pragma unroll
        for (int qf = 0; qf < 2; ++qf) o[cf][qf] = (f32x4){0.f, 0.f, 0.f, 0.f};
    f32x4 ol[2];
#pragma unroll
    for (int qf = 0; qf < 2; ++qf) ol[qf] = (f32x4){0.f, 0.f, 0.f, 0.f};
    f16x8 ones;
#pragma unroll
    for (int j = 0; j < 8; ++j) ones[j] = (_Float16)1.0f;

    f16x8 pb[2][2];
#pragma unroll
    for (int qf = 0; qf < 2; ++qf)
#pragma unroll
        for (int ks = 0; ks < 2; ++ks)
#pragma unroll
            for (int j = 0; j < 8; ++j) pb[qf][ks][j] = (_Float16)0.0f;

    const int sr0 = tid >> 3, sc0 = (tid & 7) * 8;
    const int sr1 = sr0 + 32;
    const _Float16* gK = Kf + (size_t)b * Tt * Cc + h * 64;
    const _Float16* gV = VT + ((size_t)b * Cc + h * 64) * Tt;

    f16x8 rk0, rk1, rv0, rv1;
    {
        rk0 = *(const f16x8*)&gK[(size_t)sr0 * Cc + sc0];
        rk1 = *(const f16x8*)&gK[(size_t)sr1 * Cc + sc0];
        rv0 = *(const f16x8*)&gV[(size_t)sr0 * Tt + sc0];
        rv1 = *(const f16x8*)&gV[(size_t)sr1 * Tt + sc0];
    }

#pragma unroll 2
    for (int kt = 0; kt < 32; ++kt) {
        const int cur = kt & 1, prv = cur ^ 1;
        _Float16* sKc = sK[cur];
        _Float16* sVc = sVT[cur];

        __syncthreads();
        *(f16x8*)&sKc[sr0 * LSTR + sc0] = rk0;
        *(f16x8*)&sKc[sr1 * LSTR + sc0] = rk1;
        *(f16x8*)&sVc[sr0 * LSTR + sc0] = rv0;
        *(f16x8*)&sVc[sr1 * LSTR + sc0] = rv1;
        __syncthreads();

        if (kt < 31) {
            const int t0 = (kt + 1) * 64;
            rk0 = *(const f16x8*)&gK[(size_t)(t0 + sr0) * Cc + sc0];
            rk1 = *(const f16x8*)&gK[(size_t)(t0 + sr1) * Cc + sc0];
            rv0 = *(const f16x8*)&gV[(size_t)sr0 * Tt + t0 + sc0];
            rv1 = *(const f16x8*)&gV[(size_t)sr1 * Tt + t0 + sc0];
        }

        // ---- S^T(kt) = K Q^T
        f32x4 st[4][2];
#pragma unroll
        for (int kf = 0; kf < 4; ++kf)
#pragma unroll
            for (int qf = 0; qf < 2; ++qf) st[kf][qf] = (f32x4){0.f, 0.f, 0.f, 0.f};
#pragma unroll
        for (int ks = 0; ks < 2; ++ks) {
            f16x8 ka[4];
#pragma unroll
            for (int kf = 0; kf < 4; ++kf)
                ka[kf] = *(const f16x8*)&sKc[(kf * 16 + lm) * LSTR + ks * 32 + quad * 8];
            __builtin_amdgcn_s_setprio(1);
#pragma unroll
            for (int kf = 0; kf < 4; ++kf)
#pragma unroll
                for (int qf = 0; qf < 2; ++qf)
                    st[kf][qf] = __builtin_amdgcn_mfma_f32_16x16x32_f16(ka[kf], qb[qf][ks], st[kf][qf], 0, 0, 0);
            __builtin_amdgcn_s_setprio(0);
        }

        // ---- PV(kt-1): O^T += VT P^T ; l += ones P^T
        if (kt > 0) {
            _Float16* sVp = sVT[prv];
#pragma unroll
            for (int ks = 0; ks < 2; ++ks) {
                f16x8 va[4];
#pragma unroll
                for (int cf = 0; cf < 4; ++cf)
                    va[cf] = *(const f16x8*)&sVp[(cf * 16 + lm) * LSTR + ks * 32 + quad * 8];
                __builtin_amdgcn_s_setprio(1);
#pragma unroll
                for (int cf = 0; cf < 4; ++cf)
#pragma unroll
                    for (int qf = 0; qf < 2; ++qf)
                        o[cf][qf] = __builtin_amdgcn_mfma_f32_16x16x32_f16(va[cf], pb[qf][ks], o[cf][qf], 0, 0, 0);
#pragma unroll
                for (int qf = 0; qf < 2; ++qf)
                    ol[qf] = __builtin_amdgcn_mfma_f32_16x16x32_f16(ones, pb[qf][ks], ol[qf], 0, 0, 0);
                __builtin_amdgcn_s_setprio(0);
            }
        }

        // ---- p = exp2(s(kt)) -> pb regs
#pragma unroll
        for (int ks = 0; ks < 2; ++ks)
#pragma unroll
            for (int qf = 0; qf < 2; ++qf) {
                const f32x4 a = st[2 * ks][qf];
                const f32x4 c = st[2 * ks + 1][qf];
                const f16x2 l0 = __builtin_bit_cast(f16x2, __builtin_amdgcn_cvt_pkrtz(
                    __builtin_amdgcn_exp2f(a[0]), __builtin_amdgcn_exp2f(a[1])));
                const f16x2 l1 = __builtin_bit_cast(f16x2, __builtin_amdgcn_cvt_pkrtz(
                    __builtin_amdgcn_exp2f(a[2]), __builtin_amdgcn_exp2f(a[3])));
                const f16x2 h0 = __builtin_bit_cast(f16x2, __builtin_amdgcn_cvt_pkrtz(
                    __builtin_amdgcn_exp2f(c[0]), __builtin_amdgcn_exp2f(c[1])));
                const f16x2 h1 = __builtin_bit_cast(f16x2, __builtin_amdgcn_cvt_pkrtz(
                    __builtin_amdgcn_exp2f(c[2]), __builtin_amdgcn_exp2f(c[3])));
                f16x8 p;
                p[0] = l0[0]; p[1] = l0[1]; p[2] = l1[0]; p[3] = l1[1];
                p[4] = h0[0]; p[5] = h0[1]; p[6] = h1[0]; p[7] = h1[1];
                pb[qf][ks] = p;
            }
    }

    // ---- drain PV(31)
    {
        _Float16* sVp = sVT[1];
#pragma unroll
        for (int ks = 0; ks < 2; ++ks) {
            f16x8 va[4];
#pragma unroll
            for (int cf = 0; cf < 4; ++cf)
                va[cf] = *(const f16x8*)&sVp[(cf * 16 + lm) * LSTR + ks * 32 + quad * 8];
#pragma unroll
            for (int cf = 0; cf < 4; ++cf)
#pragma unroll
                for (int qf = 0; qf < 2; ++qf)
                    o[cf][qf] = __builtin_amdgcn_mfma_f32_16x16x32_f16(va[cf], pb[qf][ks], o[cf][qf], 0, 0, 0);
#pragma unroll
            for (int qf = 0; qf < 2; ++qf)
                ol[qf] = __builtin_amdgcn_mfma_f32_16x16x32_f16(ones, pb[qf][ks], ol[qf], 0, 0, 0);
        }
    }

    // ---- epilogue: il from ones-MFMA, iv inline from colsum
    float il[2];
#pragma unroll
    for (int qf = 0; qf < 2; ++qf) il[qf] = 1.0f / ol[qf][0];
    const float* csv = colsum + 2 * BC + b * Cc + h * 64;
    float iv[4][4];
#pragma unroll
    for (int cf = 0; cf < 4; ++cf) {
        float4 t = *(const float4*)&csv[cf * 16 + quad * 4];
        iv[cf][0] = rsqrtf(t.x * invT + 1e-4f);
        iv[cf][1] = rsqrtf(t.y * invT + 1e-4f);
        iv[cf][2] = rsqrtf(t.z * invT + 1e-4f);
        iv[cf][3] = rsqrtf(t.w * invT + 1e-4f);
    }
#pragma unroll
    for (int qf = 0; qf < 2; ++qf) {
        const size_t row = (size_t)(b * Tt + qt * 128 + wave * 32 + qf * 16 + lm);
#pragma unroll
        for (int cf = 0; cf < 4; ++cf) {
            f16x4 pk;
#pragma unroll
            for (int r = 0; r < 4; ++r)
                pk[r] = (_Float16)(o[cf][qf][r] * il[qf] * iv[cf][r]);
            *(f16x4*)&AO[row * Cc + h * 64 + cf * 16 + quad * 4] = pk;
        }
    }
}

// ---------------------------------------------------------------------------
// Kernel 5: out = AO @ Wo + bo + residual. 64x128 tile, 4 waves, BK=32,
// global_load_lds staging.
// ---------------------------------------------------------------------------
__global__ __launch_bounds__(256, 2) void out_mfma(
    const _Float16* __restrict__ AO, const _Float16* __restrict__ Wt,
    const float* __restrict__ bo, const float* __restrict__ HS,
    float* __restrict__ Outp)
{
    const int mt = blockIdx.x;              // 128
    const int nt = blockIdx.y;              // 4
    const int tid = threadIdx.x;
    const int wave = tid >> 6, lane = tid & 63;
    const int quad = lane >> 4, lm = lane & 15;
    const int wm = (wave & 1) * 32, wn = (wave >> 1) * 64;

    __shared__ _Float16 sA[64 * 32];
    __shared__ _Float16 sB[128 * 32];

    f32x4 acc[2][4];
#pragma unroll
    for (int mf = 0; mf < 2; ++mf)
#pragma unroll
        for (int nf = 0; nf < 4; ++nf) acc[mf][nf] = (f32x4){0.f, 0.f, 0.f, 0.f};

    const int lr = lane >> 2;
    const int lc = (lane & 3) * 8;
    const _Float16* gaA = AO + (size_t)(mt * 64 + wave * 16 + lr) * Cc + lc;
    const _Float16* gaB = Wt + ((size_t)(3 * 512 + nt * 128 + wave * 32 + lr)) * Cc + lc;
    _Float16* ldA = &sA[wave * 512];
    _Float16* ldB = &sB[wave * 1024];

    for (int k0 = 0; k0 < Cc; k0 += 32) {
        __syncthreads();
        gl16(gaA + k0,           ldA);
        gl16(gaB + k0,           ldB);
        gl16(gaB + 16 * Cc + k0, ldB + 512);
        __syncthreads();

        f16x8 ah[2], bh[4];
#pragma unroll
        for (int mf = 0; mf < 2; ++mf)
            ah[mf] = *(const f16x8*)&sA[(wm + mf * 16 + lm) * 32 + quad * 8];
#pragma unroll
        for (int nf = 0; nf < 4; ++nf)
            bh[nf] = *(const f16x8*)&sB[(wn + nf * 16 + lm) * 32 + quad * 8];
#pragma unroll
        for (int mf = 0; mf < 2; ++mf)
#pragma unroll
            for (int nf = 0; nf < 4; ++nf)
                acc[mf][nf] = __builtin_amdgcn_mfma_f32_16x16x32_f16(ah[mf], bh[nf], acc[mf][nf], 0, 0, 0);
    }

#pragma unroll
    for (int mf = 0; mf < 2; ++mf)
#pragma unroll
        for (int r = 0; r < 4; ++r) {
            const size_t m = (size_t)(mt * 64 + wm + mf * 16 + quad * 4 + r);
#pragma unroll
            for (int nf = 0; nf < 4; ++nf) {
                const int col = nt * 128 + wn + nf * 16 + lm;
                Outp[m * Cc + col] = acc[mf][nf][r] + bo[col] + HS[m * Cc + col];
            }
        }
}

// ---------------------------------------------------------------------------
extern "C" void kernel_launch(void* const* d_in, const int* in_sizes, int n_in,
                              void* d_out, int out_size, void* d_ws,
                              size_t ws_size, hipStream_t stream)
{
    const float* HS = (const float*)d_in[0];
    const float* Wq = (const float*)d_in[1];
    const float* Wk = (const float*)d_in[2];
    const float* Wv = (const float*)d_in[3];
    const float* Wo = (const float*)d_in[4];
    const float* bo = (const float*)d_in[5];
    float* out = (float*)d_out;

    const size_t SZ = (size_t)Bb * Tt * Cc;        // 4,194,304 elements
    _Float16* Qf  = (_Float16*)d_ws;
    _Float16* Kf  = Qf + SZ;
    _Float16* VTh = Kf + SZ;
    _Float16* HSh = VTh + SZ;
    _Float16* AO  = HSh + SZ;
    _Float16* Wt  = AO + SZ;                        // 4*Cc*Cc halves
    float* colsum = (float*)(Wt + 4 * Cc * Cc);

    prep<<<2307, 256, 0, stream>>>(Wq, Wk, Wv, Wo, HS, Wt, HSh, colsum);

    qkv_mfma<<<dim3(64, 4, 3), 256, 0, stream>>>(HSh, Wt, Qf, Kf, VTh, colsum);

    attn_mfma<<<dim3(512), 256, 0, stream>>>(Qf, Kf, VTh, colsum, AO);

    out_mfma<<<dim3(128, 4), 256, 0, stream>>>(AO, Wt, bo, HS, out);
}

// Round 18
// 153.963 us; speedup vs baseline: 1.0081x; 1.0081x over previous
//
#include <hip/hip_runtime.h>

#define Tt 2048
#define Cc 512
#define Bb 4
#define BC (Bb * Cc)

typedef __attribute__((ext_vector_type(4))) float f32x4;
typedef __attribute__((ext_vector_type(8))) _Float16 f16x8;
typedef __attribute__((ext_vector_type(4))) _Float16 f16x4;
typedef __attribute__((ext_vector_type(2))) _Float16 f16x2;

// async global->LDS 16B copy: dest = wave-uniform LDS base + lane*16.
__device__ static inline void gl16(const _Float16* g, _Float16* l)
{
    __builtin_amdgcn_global_load_lds(
        (const __attribute__((address_space(1))) void*)g,
        (__attribute__((address_space(3))) void*)l, 16, 0, 0);
}

// ---------------------------------------------------------------------------
// Kernel P: fused prep — blocks [0,2048): HS fp32->fp16; [2048,2304):
// W transpose->Wt fp16; [2304,2307): colsum zero.
// ---------------------------------------------------------------------------
__global__ __launch_bounds__(256) void prep(
    const float* __restrict__ Wq, const float* __restrict__ Wk,
    const float* __restrict__ Wv, const float* __restrict__ Wo,
    const float* __restrict__ HS, _Float16* __restrict__ Wt,
    _Float16* __restrict__ HSh, float* __restrict__ colsum)
{
    const int blk = blockIdx.x;
    const int tid = threadIdx.x;
    __shared__ float tile[64][65];

    if (blk < 2048) {
        const size_t i = ((size_t)blk * 256 + tid) * 8;
        float4 a = *(const float4*)&HS[i];
        float4 b = *(const float4*)&HS[i + 4];
        f16x8 o;
        o[0] = (_Float16)a.x; o[1] = (_Float16)a.y;
        o[2] = (_Float16)a.z; o[3] = (_Float16)a.w;
        o[4] = (_Float16)b.x; o[5] = (_Float16)b.y;
        o[6] = (_Float16)b.z; o[7] = (_Float16)b.w;
        *(f16x8*)&HSh[i] = o;
    } else if (blk < 2304) {
        const int lb = blk - 2048;
        const int z = lb >> 6, x = lb & 63;
        const float* W = (z == 0) ? Wq : (z == 1) ? Wk : (z == 2) ? Wv : Wo;
        const int k0 = (x >> 3) * 64, n0 = (x & 7) * 64;
#pragma unroll
        for (int i = 0; i < 4; ++i) {
            const int idx = i * 256 + tid;
            const int kr = idx >> 4, c4 = idx & 15;
            float4 v = *(const float4*)&W[(size_t)(k0 + kr) * Cc + n0 + c4 * 4];
            tile[kr][c4 * 4 + 0] = v.x; tile[kr][c4 * 4 + 1] = v.y;
            tile[kr][c4 * 4 + 2] = v.z; tile[kr][c4 * 4 + 3] = v.w;
        }
        __syncthreads();
#pragma unroll
        for (int i = 0; i < 4; ++i) {
            const int idx = i * 256 + tid;
            const int nr = idx >> 4, k4 = idx & 15;
            f16x4 o;
            o[0] = (_Float16)tile[k4 * 4 + 0][nr];
            o[1] = (_Float16)tile[k4 * 4 + 1][nr];
            o[2] = (_Float16)tile[k4 * 4 + 2][nr];
            o[3] = (_Float16)tile[k4 * 4 + 3][nr];
            *(f16x4*)&Wt[((size_t)(z * 512 + n0 + nr)) * Cc + k0 + k4 * 4] = o;
        }
    } else {
        const int i = (blk - 2304) * 2048 + tid * 8;
        *(f32x4*)&colsum[i]     = (f32x4){0.f, 0.f, 0.f, 0.f};
        *(f32x4*)&colsum[i + 4] = (f32x4){0.f, 0.f, 0.f, 0.f};
    }
}

// ---------------------------------------------------------------------------
// Kernel 1: QKV GEMM, fp16 MFMA, 128x128 tile, 4 waves, BK=32,
// global_load_lds staging. Epilogue: Q/K fp16 store; V (z==2) is written
// DIRECTLY as VT (transposed + kappa key-permutation) via an LDS bounce.
// All z accumulate per-(b,channel) sum-of-squares.
// ---------------------------------------------------------------------------
__global__ __launch_bounds__(256, 3) void qkv_mfma(
    const _Float16* __restrict__ HSh, const _Float16* __restrict__ Wt,
    _Float16* __restrict__ Qf, _Float16* __restrict__ Kf,
    _Float16* __restrict__ VTh, float* __restrict__ colsum)
{
    const int mt = blockIdx.x;              // 64
    const int nt = blockIdx.y;              // 4
    const int z  = blockIdx.z;              // 3

    const int tid = threadIdx.x;
    const int wave = tid >> 6, lane = tid & 63;
    const int quad = lane >> 4, lm = lane & 15;
    const int wm = (wave & 1) * 64, wn = (wave >> 1) * 64;

    __shared__ _Float16 smem[128 * 136];    // 34.8 KB
    _Float16* sA = smem;                    // 128*32
    _Float16* sB = smem + 128 * 32;         // 128*32

    f32x4 acc[4][4];
#pragma unroll
    for (int mf = 0; mf < 4; ++mf)
#pragma unroll
        for (int nf = 0; nf < 4; ++nf) acc[mf][nf] = (f32x4){0.f, 0.f, 0.f, 0.f};

    const int lr = lane >> 2;
    const int lc = (lane & 3) * 8;
    const _Float16* gaA = HSh + (size_t)(mt * 128 + wave * 32 + lr) * Cc + lc;
    const _Float16* gaB = Wt + ((size_t)(z * 512 + nt * 128 + wave * 32 + lr)) * Cc + lc;
    _Float16* ldA = &sA[wave * 1024];
    _Float16* ldB = &sB[wave * 1024];

    for (int k0 = 0; k0 < Cc; k0 += 32) {
        __syncthreads();
        gl16(gaA + k0,            ldA);
        gl16(gaA + 16 * Cc + k0,  ldA + 512);
        gl16(gaB + k0,            ldB);
        gl16(gaB + 16 * Cc + k0,  ldB + 512);
        __syncthreads();

        f16x8 ah[4], bh[4];
#pragma unroll
        for (int mf = 0; mf < 4; ++mf)
            ah[mf] = *(const f16x8*)&sA[(wm + mf * 16 + lm) * 32 + quad * 8];
#pragma unroll
        for (int nf = 0; nf < 4; ++nf)
            bh[nf] = *(const f16x8*)&sB[(wn + nf * 16 + lm) * 32 + quad * 8];
#pragma unroll
        for (int mf = 0; mf < 4; ++mf)
#pragma unroll
            for (int nf = 0; nf < 4; ++nf)
                acc[mf][nf] = __builtin_amdgcn_mfma_f32_16x16x32_f16(ah[mf], bh[nf], acc[mf][nf], 0, 0, 0);
    }

    const int bidx = mt >> 4;

    // ---- colsum (all z) + Q/K store (z < 2)
    _Float16* Out = (z == 0) ? Qf : Kf;
#pragma unroll
    for (int nf = 0; nf < 4; ++nf) {
        float cs = 0.f;
#pragma unroll
        for (int mf = 0; mf < 4; ++mf)
#pragma unroll
            for (int r = 0; r < 4; ++r) {
                const float v = acc[mf][nf][r];
                cs += v * v;
                if (z < 2) {
                    const size_t idx =
                        (size_t)(mt * 128 + wm + mf * 16 + quad * 4 + r) * Cc +
                        nt * 128 + wn + nf * 16 + lm;
                    Out[idx] = (_Float16)v;
                }
            }
        cs += __shfl_xor(cs, 16, 64);
        cs += __shfl_xor(cs, 32, 64);
        if (lane < 16)
            atomicAdd(&colsum[(size_t)z * BC + bidx * Cc + nt * 128 + wn + nf * 16 + lane], cs);
    }

    // ---- z == 2: write V transposed (VT[b][c][t'], kappa-permuted t) via LDS
    if (z == 2) {
        __syncthreads();            // staging done; reuse smem as TL[c][t']
        // phase A: scatter acc -> TL[c][tperm], stride 136 halves
#pragma unroll
        for (int nf = 0; nf < 4; ++nf) {
            const int c = wn + nf * 16 + lm;
#pragma unroll
            for (int mf = 0; mf < 4; ++mf) {
                const int m0 = wm + mf * 16 + quad * 4;     // +r, r=0..3
                const int tl = m0 & 63;
                const int u = tl >> 3, j0 = tl & 7;
                const int p0 = ((u >> 2) & 1) * 32 + (u & 1) * 16 +
                               ((u >> 1) & 1) * 4 + ((j0 >= 4) ? 8 : 0);
                const int tperm = (m0 & 64) + p0;
                f16x4 pk;
#pragma unroll
                for (int r = 0; r < 4; ++r) pk[r] = (_Float16)acc[mf][nf][r];
                *(f16x4*)&smem[c * 136 + tperm] = pk;
            }
        }
        __syncthreads();
        // phase B: coalesced f16x8 stores to VT
        const int b = mt >> 4;
        const int tbase = (mt & 15) * 128;
#pragma unroll
        for (int i = 0; i < 8; ++i) {
            const int idx = i * 256 + tid;
            const int cr = idx >> 4, t8 = (idx & 15) * 8;
            f16x8 v = *(const f16x8*)&smem[cr * 136 + t8];
            *(f16x8*)&VTh[((size_t)(b * Cc) + nt * 128 + cr) * Tt + tbase + t8] = v;
        }
    }
}

// ---------------------------------------------------------------------------
// Kernel 4: fp16 MFMA flash attention (best measured: 47.2 us). 4 waves,
// 32 q/wave, BK=64 double-buffered reg staging, cross-iteration pipeline
// (QK(kt) | PV(kt-1) | exp(kt)), P in regs via pre-permuted VT, l via
// ones-MFMA, setprio on MFMA clusters, XCD-local 1-D grid.
// inv_norm fused: iq/ik/iv computed inline from colsum (rsqrt).
// ---------------------------------------------------------------------------
#define LSTR 72

__global__ __launch_bounds__(256, 3) void attn_mfma(
    const _Float16* __restrict__ Qf, const _Float16* __restrict__ Kf,
    const _Float16* __restrict__ VT, const float* __restrict__ colsum,
    _Float16* __restrict__ AO)
{
    const int bid = blockIdx.x;           // 512
    const int qt = bid >> 5;              // 16
    const int bh = bid & 31;              // 32 (bid%8 == bh%8 -> XCD locality)
    const int b = bh >> 3, h = bh & 7;
    const int tid = threadIdx.x;
    const int wave = tid >> 6, lane = tid & 63;
    const int quad = lane >> 4, lm = lane & 15;
    const float invT = 1.0f / Tt;

    __shared__ _Float16 sK[2][64 * LSTR];
    __shared__ _Float16 sVT[2][64 * LSTR];

    // ---- per-channel scale iq*ik*0.125*log2(e), computed from colsum inline
    float ss[2][8];
    {
        const float* csq = colsum + b * Cc + h * 64;
        const float* csk = colsum + BC + b * Cc + h * 64;
#pragma unroll
        for (int ks = 0; ks < 2; ++ks) {
            const int d0 = ks * 32 + quad * 8;
#pragma unroll
            for (int j = 0; j < 8; ++j) {
                const float iq = rsqrtf(csq[d0 + j] * invT + 1e-4f);
                const float ik = rsqrtf(csk[d0 + j] * invT + 1e-4f);
                ss[ks][j] = iq * ik * 0.18033688011f;
            }
        }
    }

    // ---- Q fragments (B-operand: n=lm=query, k=quad*8+j)
    f16x8 qb[2][2];
    {
#pragma unroll
        for (int qf = 0; qf < 2; ++qf) {
            const int row = qt * 128 + wave * 32 + qf * 16 + lm;
#pragma unroll
            for (int ks = 0; ks < 2; ++ks) {
                const int d0 = ks * 32 + quad * 8;
                f16x8 qv = *(const f16x8*)&Qf[(size_t)(b * Tt + row) * Cc + h * 64 + d0];
#pragma unroll
                for (int j = 0; j < 8; ++j)
                    qb[qf][ks][j] = (_Float16)((float)qv[j] * ss[ks][j]);
            }
        }
    }

    f32x4 o[4][2];
#pragma unroll
    for (int cf = 0; cf < 4; ++cf)
#pragma unroll
        for (int qf = 0; qf < 2; ++qf) o[cf][qf] = (f32x4){0.f, 0.f, 0.f, 0.f};
    f32x4 ol[2];
#pragma unroll
    for (int qf = 0; qf < 2; ++qf) ol[qf] = (f32x4){0.f, 0.f, 0.f, 0.f};
    f16x8 ones;
#pragma unroll
    for (int j = 0; j < 8; ++j) ones[j] = (_Float16)1.0f;

    f16x8 pb[2][2];
#pragma unroll
    for (int qf = 0; qf < 2; ++qf)
#pragma unroll
        for (int ks = 0; ks < 2; ++ks)
#pragma unroll
            for (int j = 0; j < 8; ++j) pb[qf][ks][j] = (_Float16)0.0f;

    const int sr0 = tid >> 3, sc0 = (tid & 7) * 8;
    const int sr1 = sr0 + 32;
    const _Float16* gK = Kf + (size_t)b * Tt * Cc + h * 64;
    const _Float16* gV = VT + ((size_t)b * Cc + h * 64) * Tt;

    f16x8 rk0, rk1, rv0, rv1;
    {
        rk0 = *(const f16x8*)&gK[(size_t)sr0 * Cc + sc0];
        rk1 = *(const f16x8*)&gK[(size_t)sr1 * Cc + sc0];
        rv0 = *(const f16x8*)&gV[(size_t)sr0 * Tt + sc0];
        rv1 = *(const f16x8*)&gV[(size_t)sr1 * Tt + sc0];
    }

#pragma unroll 2
    for (int kt = 0; kt < 32; ++kt) {
        const int cur = kt & 1, prv = cur ^ 1;
        _Float16* sKc = sK[cur];
        _Float16* sVc = sVT[cur];

        __syncthreads();
        *(f16x8*)&sKc[sr0 * LSTR + sc0] = rk0;
        *(f16x8*)&sKc[sr1 * LSTR + sc0] = rk1;
        *(f16x8*)&sVc[sr0 * LSTR + sc0] = rv0;
        *(f16x8*)&sVc[sr1 * LSTR + sc0] = rv1;
        __syncthreads();

        if (kt < 31) {
            const int t0 = (kt + 1) * 64;
            rk0 = *(const f16x8*)&gK[(size_t)(t0 + sr0) * Cc + sc0];
            rk1 = *(const f16x8*)&gK[(size_t)(t0 + sr1) * Cc + sc0];
            rv0 = *(const f16x8*)&gV[(size_t)sr0 * Tt + t0 + sc0];
            rv1 = *(const f16x8*)&gV[(size_t)sr1 * Tt + t0 + sc0];
        }

        // ---- S^T(kt) = K Q^T
        f32x4 st[4][2];
#pragma unroll
        for (int kf = 0; kf < 4; ++kf)
#pragma unroll
            for (int qf = 0; qf < 2; ++qf) st[kf][qf] = (f32x4){0.f, 0.f, 0.f, 0.f};
#pragma unroll
        for (int ks = 0; ks < 2; ++ks) {
            f16x8 ka[4];
#pragma unroll
            for (int kf = 0; kf < 4; ++kf)
                ka[kf] = *(const f16x8*)&sKc[(kf * 16 + lm) * LSTR + ks * 32 + quad * 8];
            __builtin_amdgcn_s_setprio(1);
#pragma unroll
            for (int kf = 0; kf < 4; ++kf)
#pragma unroll
                for (int qf = 0; qf < 2; ++qf)
                    st[kf][qf] = __builtin_amdgcn_mfma_f32_16x16x32_f16(ka[kf], qb[qf][ks], st[kf][qf], 0, 0, 0);
            __builtin_amdgcn_s_setprio(0);
        }

        // ---- PV(kt-1): O^T += VT P^T ; l += ones P^T
        if (kt > 0) {
            _Float16* sVp = sVT[prv];
#pragma unroll
            for (int ks = 0; ks < 2; ++ks) {
                f16x8 va[4];
#pragma unroll
                for (int cf = 0; cf < 4; ++cf)
                    va[cf] = *(const f16x8*)&sVp[(cf * 16 + lm) * LSTR + ks * 32 + quad * 8];
                __builtin_amdgcn_s_setprio(1);
#pragma unroll
                for (int cf = 0; cf < 4; ++cf)
#pragma unroll
                    for (int qf = 0; qf < 2; ++qf)
                        o[cf][qf] = __builtin_amdgcn_mfma_f32_16x16x32_f16(va[cf], pb[qf][ks], o[cf][qf], 0, 0, 0);
#pragma unroll
                for (int qf = 0; qf < 2; ++qf)
                    ol[qf] = __builtin_amdgcn_mfma_f32_16x16x32_f16(ones, pb[qf][ks], ol[qf], 0, 0, 0);
                __builtin_amdgcn_s_setprio(0);
            }
        }

        // ---- p = exp2(s(kt)) -> pb regs
#pragma unroll
        for (int ks = 0; ks < 2; ++ks)
#pragma unroll
            for (int qf = 0; qf < 2; ++qf) {
                const f32x4 a = st[2 * ks][qf];
                const f32x4 c = st[2 * ks + 1][qf];
                const f16x2 l0 = __builtin_bit_cast(f16x2, __builtin_amdgcn_cvt_pkrtz(
                    __builtin_amdgcn_exp2f(a[0]), __builtin_amdgcn_exp2f(a[1])));
                const f16x2 l1 = __builtin_bit_cast(f16x2, __builtin_amdgcn_cvt_pkrtz(
                    __builtin_amdgcn_exp2f(a[2]), __builtin_amdgcn_exp2f(a[3])));
                const f16x2 h0 = __builtin_bit_cast(f16x2, __builtin_amdgcn_cvt_pkrtz(
                    __builtin_amdgcn_exp2f(c[0]), __builtin_amdgcn_exp2f(c[1])));
                const f16x2 h1 = __builtin_bit_cast(f16x2, __builtin_amdgcn_cvt_pkrtz(
                    __builtin_amdgcn_exp2f(c[2]), __builtin_amdgcn_exp2f(c[3])));
                f16x8 p;
                p[0] = l0[0]; p[1] = l0[1]; p[2] = l1[0]; p[3] = l1[1];
                p[4] = h0[0]; p[5] = h0[1]; p[6] = h1[0]; p[7] = h1[1];
                pb[qf][ks] = p;
            }
    }

    // ---- drain PV(31)
    {
        _Float16* sVp = sVT[1];
#pragma unroll
        for (int ks = 0; ks < 2; ++ks) {
            f16x8 va[4];
#pragma unroll
            for (int cf = 0; cf < 4; ++cf)
                va[cf] = *(const f16x8*)&sVp[(cf * 16 + lm) * LSTR + ks * 32 + quad * 8];
#pragma unroll
            for (int cf = 0; cf < 4; ++cf)
#pragma unroll
                for (int qf = 0; qf < 2; ++qf)
                    o[cf][qf] = __builtin_amdgcn_mfma_f32_16x16x32_f16(va[cf], pb[qf][ks], o[cf][qf], 0, 0, 0);
#pragma unroll
            for (int qf = 0; qf < 2; ++qf)
                ol[qf] = __builtin_amdgcn_mfma_f32_16x16x32_f16(ones, pb[qf][ks], ol[qf], 0, 0, 0);
        }
    }

    // ---- epilogue: il from ones-MFMA, iv inline from colsum
    float il[2];
#pragma unroll
    for (int qf = 0; qf < 2; ++qf) il[qf] = 1.0f / ol[qf][0];
    const float* csv = colsum + 2 * BC + b * Cc + h * 64;
    float iv[4][4];
#pragma unroll
    for (int cf = 0; cf < 4; ++cf) {
        float4 t = *(const float4*)&csv[cf * 16 + quad * 4];
        iv[cf][0] = rsqrtf(t.x * invT + 1e-4f);
        iv[cf][1] = rsqrtf(t.y * invT + 1e-4f);
        iv[cf][2] = rsqrtf(t.z * invT + 1e-4f);
        iv[cf][3] = rsqrtf(t.w * invT + 1e-4f);
    }
#pragma unroll
    for (int qf = 0; qf < 2; ++qf) {
        const size_t row = (size_t)(b * Tt + qt * 128 + wave * 32 + qf * 16 + lm);
#pragma unroll
        for (int cf = 0; cf < 4; ++cf) {
            f16x4 pk;
#pragma unroll
            for (int r = 0; r < 4; ++r)
                pk[r] = (_Float16)(o[cf][qf][r] * il[qf] * iv[cf][r]);
            *(f16x4*)&AO[row * Cc + h * 64 + cf * 16 + quad * 4] = pk;
        }
    }
}

// ---------------------------------------------------------------------------
// Kernel 5: out = AO @ Wo + bo + residual. 64x128 tile, 4 waves, BK=32,
// global_load_lds staging.
// ---------------------------------------------------------------------------
__global__ __launch_bounds__(256, 2) void out_mfma(
    const _Float16* __restrict__ AO, const _Float16* __restrict__ Wt,
    const float* __restrict__ bo, const float* __restrict__ HS,
    float* __restrict__ Outp)
{
    const int mt = blockIdx.x;              // 128
    const int nt = blockIdx.y;              // 4
    const int tid = threadIdx.x;
    const int wave = tid >> 6, lane = tid & 63;
    const int quad = lane >> 4, lm = lane & 15;
    const int wm = (wave & 1) * 32, wn = (wave >> 1) * 64;

    __shared__ _Float16 sA[64 * 32];
    __shared__ _Float16 sB[128 * 32];

    f32x4 acc[2][4];
#pragma unroll
    for (int mf = 0; mf < 2; ++mf)
#pragma unroll
        for (int nf = 0; nf < 4; ++nf) acc[mf][nf] = (f32x4){0.f, 0.f, 0.f, 0.f};

    const int lr = lane >> 2;
    const int lc = (lane & 3) * 8;
    const _Float16* gaA = AO + (size_t)(mt * 64 + wave * 16 + lr) * Cc + lc;
    const _Float16* gaB = Wt + ((size_t)(3 * 512 + nt * 128 + wave * 32 + lr)) * Cc + lc;
    _Float16* ldA = &sA[wave * 512];
    _Float16* ldB = &sB[wave * 1024];

    for (int k0 = 0; k0 < Cc; k0 += 32) {
        __syncthreads();
        gl16(gaA + k0,           ldA);
        gl16(gaB + k0,           ldB);
        gl16(gaB + 16 * Cc + k0, ldB + 512);
        __syncthreads();

        f16x8 ah[2], bh[4];
#pragma unroll
        for (int mf = 0; mf < 2; ++mf)
            ah[mf] = *(const f16x8*)&sA[(wm + mf * 16 + lm) * 32 + quad * 8];
#pragma unroll
        for (int nf = 0; nf < 4; ++nf)
            bh[nf] = *(const f16x8*)&sB[(wn + nf * 16 + lm) * 32 + quad * 8];
#pragma unroll
        for (int mf = 0; mf < 2; ++mf)
#pragma unroll
            for (int nf = 0; nf < 4; ++nf)
                acc[mf][nf] = __builtin_amdgcn_mfma_f32_16x16x32_f16(ah[mf], bh[nf], acc[mf][nf], 0, 0, 0);
    }

#pragma unroll
    for (int mf = 0; mf < 2; ++mf)
#pragma unroll
        for (int r = 0; r < 4; ++r) {
            const size_t m = (size_t)(mt * 64 + wm + mf * 16 + quad * 4 + r);
#pragma unroll
            for (int nf = 0; nf < 4; ++nf) {
                const int col = nt * 128 + wn + nf * 16 + lm;
                Outp[m * Cc + col] = acc[mf][nf][r] + bo[col] + HS[m * Cc + col];
            }
        }
}

// ---------------------------------------------------------------------------
extern "C" void kernel_launch(void* const* d_in, const int* in_sizes, int n_in,
                              void* d_out, int out_size, void* d_ws,
                              size_t ws_size, hipStream_t stream)
{
    const float* HS = (const float*)d_in[0];
    const float* Wq = (const float*)d_in[1];
    const float* Wk = (const float*)d_in[2];
    const float* Wv = (const float*)d_in[3];
    const float* Wo = (const float*)d_in[4];
    const float* bo = (const float*)d_in[5];
    float* out = (float*)d_out;

    const size_t SZ = (size_t)Bb * Tt * Cc;        // 4,194,304 elements
    _Float16* Qf  = (_Float16*)d_ws;
    _Float16* Kf  = Qf + SZ;
    _Float16* VTh = Kf + SZ;
    _Float16* HSh = VTh + SZ;
    _Float16* AO  = HSh + SZ;
    _Float16* Wt  = AO + SZ;                        // 4*Cc*Cc halves
    float* colsum = (float*)(Wt + 4 * Cc * Cc);

    prep<<<2307, 256, 0, stream>>>(Wq, Wk, Wv, Wo, HS, Wt, HSh, colsum);

    qkv_mfma<<<dim3(64, 4, 3), 256, 0, stream>>>(HSh, Wt, Qf, Kf, VTh, colsum);

    attn_mfma<<<dim3(512), 256, 0, stream>>>(Qf, Kf, VTh, colsum, AO);

    out_mfma<<<dim3(128, 4), 256, 0, stream>>>(AO, Wt, bo, HS, out);
}